// Round 8
// baseline (220.083 us; speedup 1.0000x reference)
//
#include <hip/hip_runtime.h>

// AttentionCore64: B=2,H=16,S=2048,D=64, fp32 in/out, softmax(QK^T)V, NO 1/sqrt(d).
// R8: occupancy WITHOUT extra blocks. grid=512 (16 blocks/bh, locality proven
// at FETCH=24.7MB), 512-thread blocks = 2 q-subtiles x 4 KV parities ->
// 2 blocks/CU x 8 waves = 4 waves/SIMD (was 2). Per-thread work identical.
// KVB=32/parity, 128 kv rows/iter, NIT=16. dbuf staging, 1 barrier/iter.

#define LOG2E 1.44269504088896340736f

typedef _Float16 half8 __attribute__((ext_vector_type(8)));
typedef _Float16 half4 __attribute__((ext_vector_type(4)));
typedef __fp16 fp16x2 __attribute__((ext_vector_type(2)));   // cvt_pkrtz return
typedef float f32x16 __attribute__((ext_vector_type(16)));

#define BH    32
#define SEQ   2048
#define DIM   64
#define QBLK  128            // 2 q-subtiles x 64 rows
#define KVB   32             // kv rows per parity tile
#define NPAR  4              // kv parities (waves 2*wk+wq)
#define NIT   (SEQ / (NPAR * KVB))   // 16 iterations

union SMem {
  // staging: dbuf x 4 parities; K rows of 64 halves, Vt rows of 32 halves
  struct { _Float16 K[2][NPAR][KVB * DIM]; _Float16 Vt[2][NPAR][DIM * KVB]; } s; // 64 KB
  struct { float ob[2][2][4][16 * 64]; float ml[2][2][4][64]; } c;               // 72 KB
};

static __device__ __forceinline__ unsigned pk2(float a, float b) {
  fp16x2 h = __builtin_amdgcn_cvt_pkrtz(a, b);
  return __builtin_bit_cast(unsigned, h);
}

static __device__ __forceinline__ float xmax32(float x) {
  return fmaxf(x, __shfl_xor(x, 32));
}
static __device__ __forceinline__ float xsum32(float x) {
  return x + __shfl_xor(x, 32);
}

__launch_bounds__(512, 4)
__global__ void attn_fwd(const float* __restrict__ Q, const float* __restrict__ K,
                         const float* __restrict__ V, float* __restrict__ O) {
  __shared__ __align__(16) SMem sm;

  const int tid  = threadIdx.x;
  const int lane = tid & 63;
  const int wave = tid >> 6;    // 0..7
  const int wq   = wave & 1;    // q sub-tile (64 rows each)
  const int wk   = wave >> 1;   // kv parity 0..3
  const int hi   = lane >> 5;
  const int lq   = lane & 31;
  const bool hb  = (hi != 0);

  // XCD swizzle: 512 = 8 xcd * 64; 4 bh per XCD (same as R5 -> locality proven).
  const int bid  = blockIdx.x;
  const int xcd  = bid & 7;
  const int slot = bid >> 3;               // 0..63
  const int bh   = xcd + 8 * (slot >> 4);  // 0..31
  const int qt   = slot & 15;              // 0..15

  const size_t base = (size_t)bh * SEQ * DIM;
  const int qr0 = qt * QBLK + wq * 64 + lq;   // set A row; set B = +32
  const float* qpA = Q + base + (size_t)qr0 * DIM;
  const float* qpB = qpA + 32 * DIM;

  // Q fragments (B-operand of S^T = K*Q^T): lane holds Q[q][d=16c+8hi+j]
  half8 qfA[4], qfB[4];
#pragma unroll
  for (int c = 0; c < 4; ++c) {
    float4 a0 = *(const float4*)(qpA + 16 * c + 8 * hi);
    float4 a1 = *(const float4*)(qpA + 16 * c + 8 * hi + 4);
    union { unsigned u[4]; half8 v; } h;
    h.u[0] = pk2(a0.x, a0.y); h.u[1] = pk2(a0.z, a0.w);
    h.u[2] = pk2(a1.x, a1.y); h.u[3] = pk2(a1.z, a1.w);
    qfA[c] = h.v;
    float4 b0 = *(const float4*)(qpB + 16 * c + 8 * hi);
    float4 b1 = *(const float4*)(qpB + 16 * c + 8 * hi + 4);
    h.u[0] = pk2(b0.x, b0.y); h.u[1] = pk2(b0.z, b0.w);
    h.u[2] = pk2(b1.x, b1.y); h.u[3] = pk2(b1.z, b1.w);
    qfB[c] = h.v;
  }

  f32x16 oA0 = {}, oA1 = {}, oB0 = {}, oB1 = {};   // O^T: d=(r&3)+8*(r>>2)+4hi (+32), q=lq
  float mA = -1e30f, lA = 0.f, mB = -1e30f, lB = 0.f;

  // ---- staging: per iteration 4 parity tiles (128 kv rows) over 512 threads.
  // K: thread covers float4 at e=tid*4 within the 32x64 parity tile.
  // V: thread covers 4 strided floats (d=vd, k=vk0..vk0+3).
  float4 kreg[NPAR];
  float  vreg[NPAR][4];
  const int kr  = (tid * 4) >> 6;    // K row (0..31)
  const int kd  = (tid * 4) & 63;    // K d-offset (4-aligned)
  const int vd  = tid & 63;          // V^T row (d)
  const int vk0 = (tid >> 6) * 4;    // V^T k-offset (0..28)
  const float* kbp = K + base;
  const float* vbp = V + base;

  auto LOADT = [&](int it) {
#pragma unroll
    for (int p = 0; p < NPAR; ++p) {
      const int t = NPAR * it + p;
      kreg[p] = *(const float4*)(kbp + (size_t)(t * KVB + kr) * DIM + kd);
      const float* vp = vbp + (size_t)(t * KVB + vk0) * DIM + vd;
#pragma unroll
      for (int j = 0; j < 4; ++j) vreg[p][j] = vp[j * DIM];
    }
  };

  // K swizzle (row=64 halves): bits 3-5 by (kr&7)  [proven R5]
  // Vt swizzle (row=32 halves): bits 3-4 by ((vd>>1)&3); d-parity supplies bank
  // bit4 via the 16-word row stride -> 8 bank groups, ~4-way residual.
  auto STORET = [&](int b) {
#pragma unroll
    for (int p = 0; p < NPAR; ++p) {
      union { unsigned u[2]; half4 v; } h;
      h.u[0] = pk2(kreg[p].x, kreg[p].y);
      h.u[1] = pk2(kreg[p].z, kreg[p].w);
      const int idx = (kr * DIM + kd) ^ ((kr & 7) << 3);
      *(half4*)&sm.s.K[b][p][idx] = h.v;
      union { unsigned u[2]; half4 v; } g;
      g.u[0] = pk2(vreg[p][0], vreg[p][1]);
      g.u[1] = pk2(vreg[p][2], vreg[p][3]);
      const int vidx = (vd * KVB + vk0) ^ (((vd >> 1) & 3) << 3);
      *(half4*)&sm.s.Vt[b][p][vidx] = g.v;
    }
  };

  // softmax for one fragment set; emits PV B-fragments pv0 (k0..15), pv1 (k16..31)
  auto softmax_set = [&](const f32x16& s, float& m, float& l,
                         f32x16& o0, f32x16& o1, half8& pv0, half8& pv1) {
    float x0 = fmaxf(fmaxf(s[0], s[1]), fmaxf(s[2], s[3]));
    float x1 = fmaxf(fmaxf(s[4], s[5]), fmaxf(s[6], s[7]));
    float x2 = fmaxf(fmaxf(s[8], s[9]), fmaxf(s[10], s[11]));
    float x3 = fmaxf(fmaxf(s[12], s[13]), fmaxf(s[14], s[15]));
    float t = xmax32(fmaxf(fmaxf(x0, x1), fmaxf(x2, x3)));
    if (__any(t > m + 8.f)) {          // defer-max
      const float mn = fmaxf(m, t);
      const float corr = __builtin_amdgcn_exp2f((m - mn) * LOG2E);
      m = mn; l *= corr;
#pragma unroll
      for (int i = 0; i < 16; ++i) { o0[i] *= corr; o1[i] *= corr; }
    }
    const float nml2 = -m * LOG2E;
    float p[16];
#pragma unroll
    for (int i = 0; i < 16; ++i)
      p[i] = __builtin_amdgcn_exp2f(__builtin_fmaf(s[i], LOG2E, nml2));
    float t0 = (p[0] + p[1]) + (p[2] + p[3]);
    float t1 = (p[4] + p[5]) + (p[6] + p[7]);
    float t2 = (p[8] + p[9]) + (p[10] + p[11]);
    float t3 = (p[12] + p[13]) + (p[14] + p[15]);
    l += xsum32((t0 + t1) + (t2 + t3));

    unsigned w[8];
#pragma unroll
    for (int i = 0; i < 8; ++i) w[i] = pk2(p[2 * i], p[2 * i + 1]);
    // pair exchange (w0<->w2),(w1<->w3),(w4<->w6),(w5<->w7): one shuffle each.
    unsigned y0 = hb ? w[0] : w[2];  unsigned r0 = (unsigned)__shfl_xor((int)y0, 32);
    unsigned y1 = hb ? w[1] : w[3];  unsigned r1 = (unsigned)__shfl_xor((int)y1, 32);
    unsigned y2 = hb ? w[4] : w[6];  unsigned r2 = (unsigned)__shfl_xor((int)y2, 32);
    unsigned y3 = hb ? w[5] : w[7];  unsigned r3 = (unsigned)__shfl_xor((int)y3, 32);
    union { unsigned u[4]; half8 v; } f;
    f.u[0] = hb ? r0 : w[0];
    f.u[1] = hb ? r1 : w[1];
    f.u[2] = hb ? w[2] : r0;
    f.u[3] = hb ? w[3] : r1;
    pv0 = f.v;
    f.u[0] = hb ? r2 : w[4];
    f.u[1] = hb ? r3 : w[5];
    f.u[2] = hb ? w[6] : r2;
    f.u[3] = hb ? w[7] : r3;
    pv1 = f.v;
  };

  // ---- prologue ----
  LOADT(0);
  STORET(0);
  if (NIT > 1) LOADT(1);
  __syncthreads();

  for (int it = 0; it < NIT; ++it) {
    if (it + 1 < NIT) {
      STORET((it + 1) & 1);            // retires under compute below
      if (it + 2 < NIT) LOADT(it + 2);
    }

    const _Float16* Kt = sm.s.K[it & 1][wk];
    const _Float16* Vt = sm.s.Vt[it & 1][wk];

    // ---- QK^T: each K fragment feeds both q-sets (2 MFMAs per LDS read)
    const int ksw = (lq & 7) << 3;
    f32x16 sA = {}, sB = {};
    __builtin_amdgcn_s_setprio(1);
#pragma unroll
    for (int c = 0; c < 4; ++c) {
      half8 a = *(const half8*)&Kt[(lq * DIM + c * 16 + hi * 8) ^ ksw];
      sA = __builtin_amdgcn_mfma_f32_32x32x16_f16(a, qfA[c], sA, 0, 0, 0);
      sB = __builtin_amdgcn_mfma_f32_32x32x16_f16(a, qfB[c], sB, 0, 0, 0);
    }
    __builtin_amdgcn_s_setprio(0);

    half8 pA0, pA1, pB0, pB1;
    softmax_set(sA, mA, lA, oA0, oA1, pA0, pA1);
    softmax_set(sB, mB, lB, oB0, oB1, pB0, pB1);

    // ---- PV: each V^T fragment feeds both q-sets
    const int d0 = lq, d1 = 32 + lq;
    const int sz = ((lq >> 1) & 3) << 3;   // same for d0 and d1 (32 ≡ 0 mod 4 shift src)
    __builtin_amdgcn_s_setprio(1);
    {
      half8 a = *(const half8*)&Vt[(d0 * KVB + 0 + hi * 8) ^ sz];
      oA0 = __builtin_amdgcn_mfma_f32_32x32x16_f16(a, pA0, oA0, 0, 0, 0);
      oB0 = __builtin_amdgcn_mfma_f32_32x32x16_f16(a, pB0, oB0, 0, 0, 0);
    }
    {
      half8 a = *(const half8*)&Vt[(d1 * KVB + 0 + hi * 8) ^ sz];
      oA1 = __builtin_amdgcn_mfma_f32_32x32x16_f16(a, pA0, oA1, 0, 0, 0);
      oB1 = __builtin_amdgcn_mfma_f32_32x32x16_f16(a, pB0, oB1, 0, 0, 0);
    }
    {
      half8 a = *(const half8*)&Vt[(d0 * KVB + 16 + hi * 8) ^ sz];
      oA0 = __builtin_amdgcn_mfma_f32_32x32x16_f16(a, pA1, oA0, 0, 0, 0);
      oB0 = __builtin_amdgcn_mfma_f32_32x32x16_f16(a, pB1, oB0, 0, 0, 0);
    }
    {
      half8 a = *(const half8*)&Vt[(d1 * KVB + 16 + hi * 8) ^ sz];
      oA1 = __builtin_amdgcn_mfma_f32_32x32x16_f16(a, pA1, oA1, 0, 0, 0);
      oB1 = __builtin_amdgcn_mfma_f32_32x32x16_f16(a, pB1, oB1, 0, 0, 0);
    }
    __builtin_amdgcn_s_setprio(0);

    __syncthreads();   // single barrier per iteration
  }

  // ---- 4-way combine per q-subtile, pairwise tree (slots in LDS union) ----
  auto publish = [&](int s) {
#pragma unroll
    for (int r = 0; r < 16; ++r) {
      sm.c.ob[wq][s][0][r * 64 + lane] = oA0[r];
      sm.c.ob[wq][s][1][r * 64 + lane] = oA1[r];
      sm.c.ob[wq][s][2][r * 64 + lane] = oB0[r];
      sm.c.ob[wq][s][3][r * 64 + lane] = oB1[r];
    }
    sm.c.ml[wq][s][0][lane] = mA; sm.c.ml[wq][s][1][lane] = lA;
    sm.c.ml[wq][s][2][lane] = mB; sm.c.ml[wq][s][3][lane] = lB;
  };
  auto merge = [&](int s) {
    {
      const float mb = sm.c.ml[wq][s][0][lane], lb = sm.c.ml[wq][s][1][lane];
      const float mx = fmaxf(mA, mb);
      const float ca = __builtin_amdgcn_exp2f((mA - mx) * LOG2E);
      const float cb = __builtin_amdgcn_exp2f((mb - mx) * LOG2E);
#pragma unroll
      for (int r = 0; r < 16; ++r) {
        oA0[r] = oA0[r] * ca + sm.c.ob[wq][s][0][r * 64 + lane] * cb;
        oA1[r] = oA1[r] * ca + sm.c.ob[wq][s][1][r * 64 + lane] * cb;
      }
      lA = lA * ca + lb * cb; mA = mx;
    }
    {
      const float mb = sm.c.ml[wq][s][2][lane], lb = sm.c.ml[wq][s][3][lane];
      const float mx = fmaxf(mB, mb);
      const float ca = __builtin_amdgcn_exp2f((mB - mx) * LOG2E);
      const float cb = __builtin_amdgcn_exp2f((mb - mx) * LOG2E);
#pragma unroll
      for (int r = 0; r < 16; ++r) {
        oB0[r] = oB0[r] * ca + sm.c.ob[wq][s][2][r * 64 + lane] * cb;
        oB1[r] = oB1[r] * ca + sm.c.ob[wq][s][3][r * 64 + lane] * cb;
      }
      lB = lB * ca + lb * cb; mB = mx;
    }
  };

  // union reuse safe: loop-final barrier done
  if (wk == 1) publish(0);
  if (wk == 3) publish(1);
  __syncthreads();
  if (wk == 0) merge(0);
  if (wk == 2) merge(1);
  __syncthreads();                       // slot0 fully read before overwrite
  if (wk == 2) publish(0);
  __syncthreads();
  if (wk == 0) {
    merge(0);
    const float invA = 1.0f / lA;
    const float invB = 1.0f / lB;
    float* opA = O + base + (size_t)qr0 * DIM;
    float* opB = opA + 32 * DIM;
#pragma unroll
    for (int g = 0; g < 4; ++g) {
      float4 r0, r1;
      r0.x = oA0[4*g+0] * invA; r0.y = oA0[4*g+1] * invA;
      r0.z = oA0[4*g+2] * invA; r0.w = oA0[4*g+3] * invA;
      r1.x = oA1[4*g+0] * invA; r1.y = oA1[4*g+1] * invA;
      r1.z = oA1[4*g+2] * invA; r1.w = oA1[4*g+3] * invA;
      *(float4*)(opA + 8 * g + 4 * hi) = r0;        // d = 8g+4hi..+3
      *(float4*)(opA + 32 + 8 * g + 4 * hi) = r1;   // d = 32+8g+4hi..+3
      r0.x = oB0[4*g+0] * invB; r0.y = oB0[4*g+1] * invB;
      r0.z = oB0[4*g+2] * invB; r0.w = oB0[4*g+3] * invB;
      r1.x = oB1[4*g+0] * invB; r1.y = oB1[4*g+1] * invB;
      r1.z = oB1[4*g+2] * invB; r1.w = oB1[4*g+3] * invB;
      *(float4*)(opB + 8 * g + 4 * hi) = r0;
      *(float4*)(opB + 32 + 8 * g + 4 * hi) = r1;
    }
  }
}

extern "C" void kernel_launch(void* const* d_in, const int* in_sizes, int n_in,
                              void* d_out, int out_size, void* d_ws, size_t ws_size,
                              hipStream_t stream) {
  const float* q = (const float*)d_in[0];
  const float* k = (const float*)d_in[1];
  const float* v = (const float*)d_in[2];
  float* o = (float*)d_out;
  attn_fwd<<<BH * (SEQ / QBLK), 512, 0, stream>>>(q, k, v, o);
}

// Round 9
// 88.003 us; speedup vs baseline: 2.5009x; 2.5009x over previous
//
#include <hip/hip_runtime.h>

// AttentionCore64: B=2,H=16,S=2048,D=64, fp32 in/out, softmax(QK^T)V, NO 1/sqrt(d).
// R9: R6 kernel verbatim EXCEPT __launch_bounds__(256,2) (was (256,3)).
// R6/R8 failed from launch-bounds VGPR clamps (84/64 regs -> massive scratch
// spill = the 280-510MB "FETCH"). Cap 128 fits the ~116 needed -> genuine
// 4 blocks/CU occupancy test. QBLK=64, 4 waves = 4 KV parities, grid 1024.

#define LOG2E 1.44269504088896340736f

typedef _Float16 half8 __attribute__((ext_vector_type(8)));
typedef __fp16 fp16x2 __attribute__((ext_vector_type(2)));   // cvt_pkrtz return
typedef float f32x16 __attribute__((ext_vector_type(16)));

#define BH   32
#define SEQ  2048
#define DIM  64
#define QBLK 64              // q rows per block; each wave covers all (2 sets)
#define KVB  32              // kv rows per parity tile
#define NPAR 4               // kv parities = waves
#define NIT  (SEQ / (NPAR * KVB))   // 16 iterations

union SMem {
  struct { _Float16 K[NPAR][KVB * DIM]; _Float16 Vt[NPAR][DIM * KVB]; } s; // 32 KB
  struct { float ob[2][4][16 * 64]; float ml[2][4][64]; } c;               // 34 KB
};

static __device__ __forceinline__ unsigned pk2(float a, float b) {
  fp16x2 h = __builtin_amdgcn_cvt_pkrtz(a, b);
  return __builtin_bit_cast(unsigned, h);
}

static __device__ __forceinline__ float xmax32(float x) {
  return fmaxf(x, __shfl_xor(x, 32));
}
static __device__ __forceinline__ float xsum32(float x) {
  return x + __shfl_xor(x, 32);
}

__launch_bounds__(256, 2)
__global__ void attn_fwd(const float* __restrict__ Q, const float* __restrict__ K,
                         const float* __restrict__ V, float* __restrict__ O) {
  __shared__ __align__(16) SMem sm;

  const int tid  = threadIdx.x;
  const int lane = tid & 63;
  const int wk   = tid >> 6;    // kv parity (= wave)
  const int hi   = lane >> 5;
  const int lq   = lane & 31;
  const bool hb  = (hi != 0);

  // XCD swizzle: 1024 = 8 xcd * 128; 4 bh per XCD.
  const int bid  = blockIdx.x;
  const int xcd  = bid & 7;
  const int slot = bid >> 3;               // 0..127
  const int bh   = xcd + 8 * (slot >> 5);  // 0..31
  const int qt   = slot & 31;              // 0..31

  const size_t base = (size_t)bh * SEQ * DIM;
  const int qr0 = qt * QBLK + lq;          // set A row; set B = +32
  const float* qpA = Q + base + (size_t)qr0 * DIM;
  const float* qpB = qpA + 32 * DIM;

  // Q fragments (B-operand of S^T = K*Q^T): lane holds Q[q][d=16c+8hi+j]
  half8 qfA[4], qfB[4];
#pragma unroll
  for (int c = 0; c < 4; ++c) {
    float4 a0 = *(const float4*)(qpA + 16 * c + 8 * hi);
    float4 a1 = *(const float4*)(qpA + 16 * c + 8 * hi + 4);
    union { unsigned u[4]; half8 v; } h;
    h.u[0] = pk2(a0.x, a0.y); h.u[1] = pk2(a0.z, a0.w);
    h.u[2] = pk2(a1.x, a1.y); h.u[3] = pk2(a1.z, a1.w);
    qfA[c] = h.v;
    float4 b0 = *(const float4*)(qpB + 16 * c + 8 * hi);
    float4 b1 = *(const float4*)(qpB + 16 * c + 8 * hi + 4);
    h.u[0] = pk2(b0.x, b0.y); h.u[1] = pk2(b0.z, b0.w);
    h.u[2] = pk2(b1.x, b1.y); h.u[3] = pk2(b1.z, b1.w);
    qfB[c] = h.v;
  }

  f32x16 oA0 = {}, oA1 = {}, oB0 = {}, oB1 = {};   // O^T: d=(r&3)+8*(r>>2)+4hi (+32), q=lq
  float mA = -1e30f, lA = 0.f, mB = -1e30f, lB = 0.f;

  // ---- prefetch regs: stage all 4 parity tiles of K and V per iteration ----
  float4 kreg[NPAR][2];
  float  vreg[NPAR][8];
  const int kr  = tid >> 3;          // K row (0..31)
  const int kd  = (tid & 7) * 8;     // K d-offset
  const int vd  = tid & 63;          // V^T row (d)
  const int vk0 = (tid >> 6) * 8;    // V^T k-offset
  const float* kbp = K + base;
  const float* vbp = V + base;

  auto LOADT = [&](int it) {
#pragma unroll
    for (int p = 0; p < NPAR; ++p) {
      const int t = NPAR * it + p;
      const float* kp = kbp + (size_t)(t * KVB + kr) * DIM + kd;
      kreg[p][0] = *(const float4*)(kp);
      kreg[p][1] = *(const float4*)(kp + 4);
      const float* vp = vbp + (size_t)(t * KVB + vk0) * DIM + vd;
#pragma unroll
      for (int j = 0; j < 8; ++j) vreg[p][j] = vp[j * DIM];
    }
  };

  auto STORET = [&]() {
#pragma unroll
    for (int p = 0; p < NPAR; ++p) {
      union { unsigned u[4]; half8 v; } h;
      h.u[0] = pk2(kreg[p][0].x, kreg[p][0].y);
      h.u[1] = pk2(kreg[p][0].z, kreg[p][0].w);
      h.u[2] = pk2(kreg[p][1].x, kreg[p][1].y);
      h.u[3] = pk2(kreg[p][1].z, kreg[p][1].w);
      const int idx = (kr * DIM + kd) ^ ((kr & 7) << 3);
      *(half8*)&sm.s.K[p][idx] = h.v;
      union { unsigned u[4]; half8 v; } g;
      g.u[0] = pk2(vreg[p][0], vreg[p][1]);
      g.u[1] = pk2(vreg[p][2], vreg[p][3]);
      g.u[2] = pk2(vreg[p][4], vreg[p][5]);
      g.u[3] = pk2(vreg[p][6], vreg[p][7]);
      const int vidx = (vd * KVB + vk0) ^ ((vd & 7) << 3);
      *(half8*)&sm.s.Vt[p][vidx] = g.v;
    }
  };

  // softmax for one fragment set; emits PV B-fragments pv0 (k0..15), pv1 (k16..31)
  auto softmax_set = [&](const f32x16& s, float& m, float& l,
                         f32x16& o0, f32x16& o1, half8& pv0, half8& pv1) {
    float x0 = fmaxf(fmaxf(s[0], s[1]), fmaxf(s[2], s[3]));
    float x1 = fmaxf(fmaxf(s[4], s[5]), fmaxf(s[6], s[7]));
    float x2 = fmaxf(fmaxf(s[8], s[9]), fmaxf(s[10], s[11]));
    float x3 = fmaxf(fmaxf(s[12], s[13]), fmaxf(s[14], s[15]));
    float t = xmax32(fmaxf(fmaxf(x0, x1), fmaxf(x2, x3)));
    if (__any(t > m + 8.f)) {          // defer-max
      const float mn = fmaxf(m, t);
      const float corr = __builtin_amdgcn_exp2f((m - mn) * LOG2E);
      m = mn; l *= corr;
#pragma unroll
      for (int i = 0; i < 16; ++i) { o0[i] *= corr; o1[i] *= corr; }
    }
    const float nml2 = -m * LOG2E;
    float p[16];
#pragma unroll
    for (int i = 0; i < 16; ++i)
      p[i] = __builtin_amdgcn_exp2f(__builtin_fmaf(s[i], LOG2E, nml2));
    float t0 = (p[0] + p[1]) + (p[2] + p[3]);
    float t1 = (p[4] + p[5]) + (p[6] + p[7]);
    float t2 = (p[8] + p[9]) + (p[10] + p[11]);
    float t3 = (p[12] + p[13]) + (p[14] + p[15]);
    l += xsum32((t0 + t1) + (t2 + t3));

    unsigned w[8];
#pragma unroll
    for (int i = 0; i < 8; ++i) w[i] = pk2(p[2 * i], p[2 * i + 1]);
    // pair exchange (w0<->w2),(w1<->w3),(w4<->w6),(w5<->w7): one shuffle each.
    unsigned y0 = hb ? w[0] : w[2];  unsigned r0 = (unsigned)__shfl_xor((int)y0, 32);
    unsigned y1 = hb ? w[1] : w[3];  unsigned r1 = (unsigned)__shfl_xor((int)y1, 32);
    unsigned y2 = hb ? w[4] : w[6];  unsigned r2 = (unsigned)__shfl_xor((int)y2, 32);
    unsigned y3 = hb ? w[5] : w[7];  unsigned r3 = (unsigned)__shfl_xor((int)y3, 32);
    union { unsigned u[4]; half8 v; } f;
    f.u[0] = hb ? r0 : w[0];
    f.u[1] = hb ? r1 : w[1];
    f.u[2] = hb ? w[2] : r0;
    f.u[3] = hb ? w[3] : r1;
    pv0 = f.v;
    f.u[0] = hb ? r2 : w[4];
    f.u[1] = hb ? r3 : w[5];
    f.u[2] = hb ? w[6] : r2;
    f.u[3] = hb ? w[7] : r3;
    pv1 = f.v;
  };

  LOADT(0);
  for (int it = 0; it < NIT; ++it) {
    __syncthreads();
    STORET();
    if (it + 1 < NIT) LOADT(it + 1);
    __syncthreads();

    const _Float16* Kt = sm.s.K[wk];
    const _Float16* Vt = sm.s.Vt[wk];

    // ---- QK^T: each K fragment feeds both q-sets (2 MFMAs per LDS read)
    const int ksw = (lq & 7) << 3;
    f32x16 sA = {}, sB = {};
    __builtin_amdgcn_s_setprio(1);
#pragma unroll
    for (int c = 0; c < 4; ++c) {
      half8 a = *(const half8*)&Kt[(lq * DIM + c * 16 + hi * 8) ^ ksw];
      sA = __builtin_amdgcn_mfma_f32_32x32x16_f16(a, qfA[c], sA, 0, 0, 0);
      sB = __builtin_amdgcn_mfma_f32_32x32x16_f16(a, qfB[c], sB, 0, 0, 0);
    }
    __builtin_amdgcn_s_setprio(0);

    half8 pA0, pA1, pB0, pB1;
    softmax_set(sA, mA, lA, oA0, oA1, pA0, pA1);
    softmax_set(sB, mB, lB, oB0, oB1, pB0, pB1);

    // ---- PV: each V^T fragment feeds both q-sets
    const int d0 = lq, d1 = 32 + lq;
    const int sz0 = (d0 & 7) << 3, sz1 = (d1 & 7) << 3;
    __builtin_amdgcn_s_setprio(1);
    {
      half8 a = *(const half8*)&Vt[(d0 * KVB + 0 + hi * 8) ^ sz0];
      oA0 = __builtin_amdgcn_mfma_f32_32x32x16_f16(a, pA0, oA0, 0, 0, 0);
      oB0 = __builtin_amdgcn_mfma_f32_32x32x16_f16(a, pB0, oB0, 0, 0, 0);
    }
    {
      half8 a = *(const half8*)&Vt[(d1 * KVB + 0 + hi * 8) ^ sz1];
      oA1 = __builtin_amdgcn_mfma_f32_32x32x16_f16(a, pA0, oA1, 0, 0, 0);
      oB1 = __builtin_amdgcn_mfma_f32_32x32x16_f16(a, pB0, oB1, 0, 0, 0);
    }
    {
      half8 a = *(const half8*)&Vt[(d0 * KVB + 16 + hi * 8) ^ sz0];
      oA0 = __builtin_amdgcn_mfma_f32_32x32x16_f16(a, pA1, oA0, 0, 0, 0);
      oB0 = __builtin_amdgcn_mfma_f32_32x32x16_f16(a, pB1, oB0, 0, 0, 0);
    }
    {
      half8 a = *(const half8*)&Vt[(d1 * KVB + 16 + hi * 8) ^ sz1];
      oA1 = __builtin_amdgcn_mfma_f32_32x32x16_f16(a, pA1, oA1, 0, 0, 0);
      oB1 = __builtin_amdgcn_mfma_f32_32x32x16_f16(a, pB1, oB1, 0, 0, 0);
    }
    __builtin_amdgcn_s_setprio(0);
  }

  // ---- 4-way combine, pairwise tree: (1->0, 3->2), then (2->0) ----
  auto publish = [&](int s) {
#pragma unroll
    for (int r = 0; r < 16; ++r) {
      sm.c.ob[s][0][r * 64 + lane] = oA0[r];
      sm.c.ob[s][1][r * 64 + lane] = oA1[r];
      sm.c.ob[s][2][r * 64 + lane] = oB0[r];
      sm.c.ob[s][3][r * 64 + lane] = oB1[r];
    }
    sm.c.ml[s][0][lane] = mA; sm.c.ml[s][1][lane] = lA;
    sm.c.ml[s][2][lane] = mB; sm.c.ml[s][3][lane] = lB;
  };
  auto merge = [&](int s) {
    {
      const float mb = sm.c.ml[s][0][lane], lb = sm.c.ml[s][1][lane];
      const float mx = fmaxf(mA, mb);
      const float ca = __builtin_amdgcn_exp2f((mA - mx) * LOG2E);
      const float cb = __builtin_amdgcn_exp2f((mb - mx) * LOG2E);
#pragma unroll
      for (int r = 0; r < 16; ++r) {
        oA0[r] = oA0[r] * ca + sm.c.ob[s][0][r * 64 + lane] * cb;
        oA1[r] = oA1[r] * ca + sm.c.ob[s][1][r * 64 + lane] * cb;
      }
      lA = lA * ca + lb * cb; mA = mx;
    }
    {
      const float mb = sm.c.ml[s][2][lane], lb = sm.c.ml[s][3][lane];
      const float mx = fmaxf(mB, mb);
      const float ca = __builtin_amdgcn_exp2f((mB - mx) * LOG2E);
      const float cb = __builtin_amdgcn_exp2f((mb - mx) * LOG2E);
#pragma unroll
      for (int r = 0; r < 16; ++r) {
        oB0[r] = oB0[r] * ca + sm.c.ob[s][2][r * 64 + lane] * cb;
        oB1[r] = oB1[r] * ca + sm.c.ob[s][3][r * 64 + lane] * cb;
      }
      lB = lB * ca + lb * cb; mB = mx;
    }
  };

  __syncthreads();                       // staging reads done; union reuse safe
  if (wk == 1) publish(0);
  if (wk == 3) publish(1);
  __syncthreads();
  if (wk == 0) merge(0);
  if (wk == 2) merge(1);
  __syncthreads();                       // slot0 fully read before overwrite
  if (wk == 2) publish(0);
  __syncthreads();
  if (wk == 0) {
    merge(0);
    const float invA = 1.0f / lA;
    const float invB = 1.0f / lB;
    float* opA = O + base + (size_t)qr0 * DIM;
    float* opB = opA + 32 * DIM;
#pragma unroll
    for (int g = 0; g < 4; ++g) {
      float4 r0, r1;
      r0.x = oA0[4*g+0] * invA; r0.y = oA0[4*g+1] * invA;
      r0.z = oA0[4*g+2] * invA; r0.w = oA0[4*g+3] * invA;
      r1.x = oA1[4*g+0] * invA; r1.y = oA1[4*g+1] * invA;
      r1.z = oA1[4*g+2] * invA; r1.w = oA1[4*g+3] * invA;
      *(float4*)(opA + 8 * g + 4 * hi) = r0;        // d = 8g+4hi..+3
      *(float4*)(opA + 32 + 8 * g + 4 * hi) = r1;   // d = 32+8g+4hi..+3
      r0.x = oB0[4*g+0] * invB; r0.y = oB0[4*g+1] * invB;
      r0.z = oB0[4*g+2] * invB; r0.w = oB0[4*g+3] * invB;
      r1.x = oB1[4*g+0] * invB; r1.y = oB1[4*g+1] * invB;
      r1.z = oB1[4*g+2] * invB; r1.w = oB1[4*g+3] * invB;
      *(float4*)(opB + 8 * g + 4 * hi) = r0;
      *(float4*)(opB + 32 + 8 * g + 4 * hi) = r1;
    }
  }
}

extern "C" void kernel_launch(void* const* d_in, const int* in_sizes, int n_in,
                              void* d_out, int out_size, void* d_ws, size_t ws_size,
                              hipStream_t stream) {
  const float* q = (const float*)d_in[0];
  const float* k = (const float*)d_in[1];
  const float* v = (const float*)d_in[2];
  float* o = (float*)d_out;
  attn_fwd<<<BH * (SEQ / QBLK), 256, 0, stream>>>(q, k, v, o);
}

// Round 10
// 67.338 us; speedup vs baseline: 3.2683x; 1.3069x over previous
//
#include <hip/hip_runtime.h>

// AttentionCore64: B=2,H=16,S=2048,D=64, fp32 in/out, softmax(QK^T)V, NO 1/sqrt(d).
// R10: R7 base (67us, grid=512, 4 waves = 2 q-subtiles x 2 kv-parities) +
// att[2] software pipeline: QK(t) scores held in regs across the barrier;
// per iter: STORE(t+1) -> softmax(t)[VALU] || PV(t)[MFMA] -> barrier -> QK(t+1).
// 3 LDS buffers (t%3): PV reads buf[t], STORE writes buf[t+1], QK reads buf[t+1]
// after the barrier; buf[t+2]'s last reader was PV(t-1) two barriers ago. 1 bar/iter.

#define LOG2E 1.44269504088896340736f

typedef _Float16 half8 __attribute__((ext_vector_type(8)));
typedef __fp16 fp16x2 __attribute__((ext_vector_type(2)));   // cvt_pkrtz return
typedef float f32x16 __attribute__((ext_vector_type(16)));

#define BH   32
#define SEQ  2048
#define DIM  64
#define QBLK 128             // 2 q-waves x 64 rows
#define KVB  32              // kv rows per parity tile
#define NIT  (SEQ / (2 * KVB))   // 32 iterations

union SMem {
  struct { _Float16 K[3][2][KVB * DIM]; _Float16 Vt[3][2][DIM * KVB]; } s;  // 48 KB
  struct { float ob[2][2][2][16 * 64]; float ml[2][2][2][64]; } c;          // 36 KB
};

static __device__ __forceinline__ unsigned pk2(float a, float b) {
  fp16x2 h = __builtin_amdgcn_cvt_pkrtz(a, b);
  return __builtin_bit_cast(unsigned, h);
}

static __device__ __forceinline__ float xmax32(float x) {
  return fmaxf(x, __shfl_xor(x, 32));
}
static __device__ __forceinline__ float xsum32(float x) {
  return x + __shfl_xor(x, 32);
}

__launch_bounds__(256, 2)
__global__ void attn_fwd(const float* __restrict__ Q, const float* __restrict__ K,
                         const float* __restrict__ V, float* __restrict__ O) {
  __shared__ __align__(16) SMem sm;

  const int tid  = threadIdx.x;
  const int lane = tid & 63;
  const int wave = tid >> 6;
  const int wq   = wave & 1;    // q sub-tile (64 rows)
  const int wk   = wave >> 1;   // kv parity
  const int hi   = lane >> 5;
  const int lq   = lane & 31;
  const bool hb  = (hi != 0);

  // XCD swizzle: 512 = 8 xcd * 64; all 16 q-tiles of a bh on one XCD.
  const int bid  = blockIdx.x;
  const int xcd  = bid & 7;
  const int slot = bid >> 3;               // 0..63
  const int bh   = xcd + 8 * (slot >> 4);  // 0..31
  const int qt   = slot & 15;              // 0..15

  const size_t base = (size_t)bh * SEQ * DIM;
  const int qr0 = qt * QBLK + wq * 64 + lq;   // set A row; set B = +32
  const float* qpA = Q + base + (size_t)qr0 * DIM;
  const float* qpB = qpA + 32 * DIM;

  // Q fragments (B-operand of S^T = K*Q^T): lane holds Q[q][d=16c+8hi+j]
  half8 qfA[4], qfB[4];
#pragma unroll
  for (int c = 0; c < 4; ++c) {
    float4 a0 = *(const float4*)(qpA + 16 * c + 8 * hi);
    float4 a1 = *(const float4*)(qpA + 16 * c + 8 * hi + 4);
    union { unsigned u[4]; half8 v; } h;
    h.u[0] = pk2(a0.x, a0.y); h.u[1] = pk2(a0.z, a0.w);
    h.u[2] = pk2(a1.x, a1.y); h.u[3] = pk2(a1.z, a1.w);
    qfA[c] = h.v;
    float4 b0 = *(const float4*)(qpB + 16 * c + 8 * hi);
    float4 b1 = *(const float4*)(qpB + 16 * c + 8 * hi + 4);
    h.u[0] = pk2(b0.x, b0.y); h.u[1] = pk2(b0.z, b0.w);
    h.u[2] = pk2(b1.x, b1.y); h.u[3] = pk2(b1.z, b1.w);
    qfB[c] = h.v;
  }

  f32x16 oA0 = {}, oA1 = {}, oB0 = {}, oB1 = {};   // O^T: d=(r&3)+8*(r>>2)+4hi (+32), q=lq
  float mA = -1e30f, lA = 0.f, mB = -1e30f, lB = 0.f;

  // ---- prefetch regs: stage both parity tiles of K and V per iteration ----
  float4 kreg[2][2];
  float  vreg[2][8];
  const int kr  = tid >> 3;          // K row (0..31)
  const int kd  = (tid & 7) * 8;     // K d-offset
  const int vd  = tid & 63;          // V^T row (d)
  const int vk0 = (tid >> 6) * 8;    // V^T k-offset
  const float* kbp = K + base;
  const float* vbp = V + base;

  auto LOADT = [&](int it) {
#pragma unroll
    for (int p = 0; p < 2; ++p) {
      const int t = 2 * it + p;
      const float* kp = kbp + (size_t)(t * KVB + kr) * DIM + kd;
      kreg[p][0] = *(const float4*)(kp);
      kreg[p][1] = *(const float4*)(kp + 4);
      const float* vp = vbp + (size_t)(t * KVB + vk0) * DIM + vd;
#pragma unroll
      for (int j = 0; j < 8; ++j) vreg[p][j] = vp[j * DIM];
    }
  };

  auto STORET = [&](int b) {
#pragma unroll
    for (int p = 0; p < 2; ++p) {
      union { unsigned u[4]; half8 v; } h;
      h.u[0] = pk2(kreg[p][0].x, kreg[p][0].y);
      h.u[1] = pk2(kreg[p][0].z, kreg[p][0].w);
      h.u[2] = pk2(kreg[p][1].x, kreg[p][1].y);
      h.u[3] = pk2(kreg[p][1].z, kreg[p][1].w);
      const int idx = (kr * DIM + kd) ^ ((kr & 7) << 3);
      *(half8*)&sm.s.K[b][p][idx] = h.v;
      union { unsigned u[4]; half8 v; } g;
      g.u[0] = pk2(vreg[p][0], vreg[p][1]);
      g.u[1] = pk2(vreg[p][2], vreg[p][3]);
      g.u[2] = pk2(vreg[p][4], vreg[p][5]);
      g.u[3] = pk2(vreg[p][6], vreg[p][7]);
      const int vidx = (vd * KVB + vk0) ^ ((vd & 7) << 3);
      *(half8*)&sm.s.Vt[b][p][vidx] = g.v;
    }
  };

  // QK^T of one tile from LDS buffer b -> persistent score regs
  auto QKT = [&](int b, f32x16& sA, f32x16& sB) {
    const _Float16* Kt = sm.s.K[b][wk];
    const int ksw = (lq & 7) << 3;
    sA = {}; sB = {};
    __builtin_amdgcn_s_setprio(1);
#pragma unroll
    for (int c = 0; c < 4; ++c) {
      half8 a = *(const half8*)&Kt[(lq * DIM + c * 16 + hi * 8) ^ ksw];
      sA = __builtin_amdgcn_mfma_f32_32x32x16_f16(a, qfA[c], sA, 0, 0, 0);
      sB = __builtin_amdgcn_mfma_f32_32x32x16_f16(a, qfB[c], sB, 0, 0, 0);
    }
    __builtin_amdgcn_s_setprio(0);
  };

  // softmax for one fragment set; emits PV B-fragments pv0 (k0..15), pv1 (k16..31)
  auto softmax_set = [&](const f32x16& s, float& m, float& l,
                         f32x16& o0, f32x16& o1, half8& pv0, half8& pv1) {
    float x0 = fmaxf(fmaxf(s[0], s[1]), fmaxf(s[2], s[3]));
    float x1 = fmaxf(fmaxf(s[4], s[5]), fmaxf(s[6], s[7]));
    float x2 = fmaxf(fmaxf(s[8], s[9]), fmaxf(s[10], s[11]));
    float x3 = fmaxf(fmaxf(s[12], s[13]), fmaxf(s[14], s[15]));
    float t = xmax32(fmaxf(fmaxf(x0, x1), fmaxf(x2, x3)));
    if (__any(t > m + 8.f)) {          // defer-max
      const float mn = fmaxf(m, t);
      const float corr = __builtin_amdgcn_exp2f((m - mn) * LOG2E);
      m = mn; l *= corr;
#pragma unroll
      for (int i = 0; i < 16; ++i) { o0[i] *= corr; o1[i] *= corr; }
    }
    const float nml2 = -m * LOG2E;
    float p[16];
#pragma unroll
    for (int i = 0; i < 16; ++i)
      p[i] = __builtin_amdgcn_exp2f(__builtin_fmaf(s[i], LOG2E, nml2));
    float t0 = (p[0] + p[1]) + (p[2] + p[3]);
    float t1 = (p[4] + p[5]) + (p[6] + p[7]);
    float t2 = (p[8] + p[9]) + (p[10] + p[11]);
    float t3 = (p[12] + p[13]) + (p[14] + p[15]);
    l += xsum32((t0 + t1) + (t2 + t3));

    unsigned w[8];
#pragma unroll
    for (int i = 0; i < 8; ++i) w[i] = pk2(p[2 * i], p[2 * i + 1]);
    // pair exchange (w0<->w2),(w1<->w3),(w4<->w6),(w5<->w7): one shuffle each.
    unsigned y0 = hb ? w[0] : w[2];  unsigned r0 = (unsigned)__shfl_xor((int)y0, 32);
    unsigned y1 = hb ? w[1] : w[3];  unsigned r1 = (unsigned)__shfl_xor((int)y1, 32);
    unsigned y2 = hb ? w[4] : w[6];  unsigned r2 = (unsigned)__shfl_xor((int)y2, 32);
    unsigned y3 = hb ? w[5] : w[7];  unsigned r3 = (unsigned)__shfl_xor((int)y3, 32);
    union { unsigned u[4]; half8 v; } f;
    f.u[0] = hb ? r0 : w[0];
    f.u[1] = hb ? r1 : w[1];
    f.u[2] = hb ? w[2] : r0;
    f.u[3] = hb ? w[3] : r1;
    pv0 = f.v;
    f.u[0] = hb ? r2 : w[4];
    f.u[1] = hb ? r3 : w[5];
    f.u[2] = hb ? w[6] : r2;
    f.u[3] = hb ? w[7] : r3;
    pv1 = f.v;
  };

  // ---- prologue: buf0 <- tile0; regs <- tile1; QK(tile0) ----
  LOADT(0);
  STORET(0);
  LOADT(1);
  __syncthreads();
  f32x16 sAp, sBp;
  QKT(0, sAp, sBp);

  for (int it = 0; it < NIT; ++it) {
    const int bcur = it % 3, bnext = (it + 1) % 3;
    // STORE tile it+1 (regs loaded 2 iters ago); LOAD tile it+2.
    // buf[bnext]'s last reader: PV(it-2) at iter it-2 (two barriers ago). Safe.
    if (it + 1 < NIT) {
      STORET(bnext);
      if (it + 2 < NIT) LOADT(it + 2);
    }

    // softmax(tile it) on VALU — overlaps ds_write retirement and PV below
    half8 pA0, pA1, pB0, pB1;
    softmax_set(sAp, mA, lA, oA0, oA1, pA0, pA1);
    softmax_set(sBp, mB, lB, oB0, oB1, pB0, pB1);

    // PV(tile it) from buf[bcur]
    const _Float16* Vt = sm.s.Vt[bcur][wk];
    const int d0 = lq, d1 = 32 + lq;
    const int sz0 = (d0 & 7) << 3, sz1 = (d1 & 7) << 3;
    __builtin_amdgcn_s_setprio(1);
    {
      half8 a = *(const half8*)&Vt[(d0 * KVB + 0 + hi * 8) ^ sz0];
      oA0 = __builtin_amdgcn_mfma_f32_32x32x16_f16(a, pA0, oA0, 0, 0, 0);
      oB0 = __builtin_amdgcn_mfma_f32_32x32x16_f16(a, pB0, oB0, 0, 0, 0);
    }
    {
      half8 a = *(const half8*)&Vt[(d1 * KVB + 0 + hi * 8) ^ sz1];
      oA1 = __builtin_amdgcn_mfma_f32_32x32x16_f16(a, pA0, oA1, 0, 0, 0);
      oB1 = __builtin_amdgcn_mfma_f32_32x32x16_f16(a, pB0, oB1, 0, 0, 0);
    }
    {
      half8 a = *(const half8*)&Vt[(d0 * KVB + 16 + hi * 8) ^ sz0];
      oA0 = __builtin_amdgcn_mfma_f32_32x32x16_f16(a, pA1, oA0, 0, 0, 0);
      oB0 = __builtin_amdgcn_mfma_f32_32x32x16_f16(a, pB1, oB0, 0, 0, 0);
    }
    {
      half8 a = *(const half8*)&Vt[(d1 * KVB + 16 + hi * 8) ^ sz1];
      oA1 = __builtin_amdgcn_mfma_f32_32x32x16_f16(a, pA1, oA1, 0, 0, 0);
      oB1 = __builtin_amdgcn_mfma_f32_32x32x16_f16(a, pB1, oB1, 0, 0, 0);
    }
    __builtin_amdgcn_s_setprio(0);

    // barrier: buf[bnext] staged by all waves -> QK(tile it+1)
    if (it + 1 < NIT) {
      __syncthreads();
      QKT(bnext, sAp, sBp);
    }
  }

  // ---- combine kv-parities via LDS (union reuse after all staging reads) ----
  __syncthreads();
  if (wk == 1) {
#pragma unroll
    for (int r = 0; r < 16; ++r) {
      sm.c.ob[wq][0][0][r * 64 + lane] = oA0[r];
      sm.c.ob[wq][0][1][r * 64 + lane] = oA1[r];
      sm.c.ob[wq][1][0][r * 64 + lane] = oB0[r];
      sm.c.ob[wq][1][1][r * 64 + lane] = oB1[r];
    }
    sm.c.ml[wq][0][0][lane] = mA; sm.c.ml[wq][0][1][lane] = lA;
    sm.c.ml[wq][1][0][lane] = mB; sm.c.ml[wq][1][1][lane] = lB;
  }
  __syncthreads();
  if (wk == 0) {
    auto emit = [&](int set, int qrow, const f32x16& o0, const f32x16& o1,
                    float m, float l) {
      const float mb = sm.c.ml[wq][set][0][lane];
      const float lb = sm.c.ml[wq][set][1][lane];
      const float mx = fmaxf(m, mb);
      const float ca = __builtin_amdgcn_exp2f((m - mx) * LOG2E);
      const float cb = __builtin_amdgcn_exp2f((mb - mx) * LOG2E);
      const float inv = 1.0f / (l * ca + lb * cb);
      float* op = O + base + (size_t)qrow * DIM;
#pragma unroll
      for (int g = 0; g < 4; ++g) {
        float4 r0, r1;
        r0.x = (o0[4*g+0] * ca + sm.c.ob[wq][set][0][(4*g+0)*64 + lane] * cb) * inv;
        r0.y = (o0[4*g+1] * ca + sm.c.ob[wq][set][0][(4*g+1)*64 + lane] * cb) * inv;
        r0.z = (o0[4*g+2] * ca + sm.c.ob[wq][set][0][(4*g+2)*64 + lane] * cb) * inv;
        r0.w = (o0[4*g+3] * ca + sm.c.ob[wq][set][0][(4*g+3)*64 + lane] * cb) * inv;
        r1.x = (o1[4*g+0] * ca + sm.c.ob[wq][set][1][(4*g+0)*64 + lane] * cb) * inv;
        r1.y = (o1[4*g+1] * ca + sm.c.ob[wq][set][1][(4*g+1)*64 + lane] * cb) * inv;
        r1.z = (o1[4*g+2] * ca + sm.c.ob[wq][set][1][(4*g+2)*64 + lane] * cb) * inv;
        r1.w = (o1[4*g+3] * ca + sm.c.ob[wq][set][1][(4*g+3)*64 + lane] * cb) * inv;
        *(float4*)(op + 8 * g + 4 * hi) = r0;        // d = 8g+4hi..+3
        *(float4*)(op + 32 + 8 * g + 4 * hi) = r1;   // d = 32+8g+4hi..+3
      }
    };
    emit(0, qr0,      oA0, oA1, mA, lA);
    emit(1, qr0 + 32, oB0, oB1, mB, lB);
  }
}

extern "C" void kernel_launch(void* const* d_in, const int* in_sizes, int n_in,
                              void* d_out, int out_size, void* d_ws, size_t ws_size,
                              hipStream_t stream) {
  const float* q = (const float*)d_in[0];
  const float* k = (const float*)d_in[1];
  const float* v = (const float*)d_in[2];
  float* o = (float*)d_out;
  attn_fwd<<<BH * (SEQ / QBLK), 256, 0, stream>>>(q, k, v, o);
}